// Round 5
// baseline (49.696 us; speedup 1.0000x reference)
//
#include <hip/hip_runtime.h>
#include <math.h>

#define NEGV (-1.0e9f)
#define HP 65   // padded histogram row (kills stride-64 bank conflicts)

__device__ __forceinline__ float clip1000(float v) {
  return fminf(fmaxf(v, -1000.0f), 1000.0f);
}

__launch_bounds__(1024, 1)
__global__ void sim_kernel(const int* __restrict__ tables,
                           const int* __restrict__ sigma,
                           const int* __restrict__ x,
                           const int* __restrict__ base_obs,
                           const float* __restrict__ W1,
                           const float* __restrict__ b1,
                           const float* __restrict__ W2,
                           const float* __restrict__ b2,
                           const int* __restrict__ max_steps_p,
                           float* __restrict__ out,
                           int B, int V, int N)
{
  const int b = blockIdx.x;
  const int tid = threadIdx.x;
  const int T = max_steps_p[0];

  __shared__ unsigned short s_pos[8192];   // candidate positions (in-place compacted)
  __shared__ int s_gidx[8192];             // initial global indices
  __shared__ int s_lab[256 * 33];          // cached labels [pos][view], stride 33
  __shared__ int s_h[2][32 * HP];          // double-buffered histograms
  __shared__ int s_surv[256];              // per-chunk survival flags
  __shared__ float s_w1a[128], s_w1b[128], s_w1c[128], s_b1v[128], s_w2v[128];
  __shared__ float s_z[33];
  __shared__ float s_zc[6];                // precomputed tail z constants
  __shared__ int s_used[32];
  __shared__ int s_ycnt[32];
  __shared__ int s_resp[32];
  __shared__ float s_b2v;
  __shared__ int s_nact, s_cnt, s_a, s_r;

  const int* tb = tables + (size_t)b * V * N;
  const int* sg = sigma + (size_t)b * N;
  const int bo = base_obs[b];
  const int xb = x[b];

  // ---------------- phase A: weights, responses, zeros ----------------
  if (tid < 128) s_w1a[tid] = W1[tid];
  else if (tid < 256) s_w1b[tid - 128] = W1[tid];
  else if (tid < 384) s_w1c[tid - 256] = W1[tid];
  else if (tid < 512) s_b1v[tid - 384] = b1[tid - 384];
  else if (tid < 640) s_w2v[tid - 512] = W2[tid - 512];
  else if (tid == 640) s_b2v = b2[0];
  else if (tid >= 704 && tid < 736) s_resp[tid - 704] = tb[(size_t)(tid - 704) * N + xb];
  for (int i = tid; i < 2 * 32 * HP; i += 1024) ((int*)s_h)[i] = 0;
  if (tid < 32) { s_used[tid] = 0; s_ycnt[tid] = 0; }
  if (tid == 0) s_nact = 0;
  __syncthreads();

  // ---------------- phase SCAN: m0 scan (tid<928) + tail-z consts (tid>=928) ----------------
  if (tid < 928) {
    const int4* tb4 = (const int4*)tb;
    for (int q = tid; q < (N >> 2); q += 928) {
      int4 v4 = tb4[q]; int base = q << 2;
      if (v4.x == bo) { int p = atomicAdd(&s_nact, 1); s_gidx[p] = base; }
      if (v4.y == bo) { int p = atomicAdd(&s_nact, 1); s_gidx[p] = base + 1; }
      if (v4.z == bo) { int p = atomicAdd(&s_nact, 1); s_gidx[p] = base + 2; }
      if (v4.w == bo) { int p = atomicAdd(&s_nact, 1); s_gidx[p] = base + 3; }
    }
  } else {
    // 6 groups x 16 lanes: the only feature vectors reachable when nact<=2.
    // Same 16-lane tree for all 6 -> exact ties among them, as in reference.
    const int g = (tid - 928) >> 4, l = (tid - 928) & 15;
    const float zcf[6][3] = {
      {1.0f, 1.0f, 2.0f},       // A: view, es=2  (log2(2)=1 exact)
      {0.0f, 0.0f, 1.0f},       // B: view es=1; stop(closed, total=1)
      {1000.0f, 0.0f, 1.0f},    // C: view0, es0=1
      {1000.0f, 1.0f, 2.0f},    // D: view0 es0=2; stop(open, total=2)
      {0.0f, -1.0f, 0.0f},      // E: view, nact=0
      {1000.0f, -1.0f, 0.0f}};  // F: view0, nact=0
    if (g < 6) {
      const float f0 = zcf[g][0], f1 = zcf[g][1], f2 = zcf[g][2];
      float zp = 0.0f;
      {
        #pragma clang fp contract(off)
        for (int k = l * 8; k < l * 8 + 8; ++k) {
          float pre = f0 * s_w1a[k] + f1 * s_w1b[k] + f2 * s_w1c[k] + s_b1v[k];
          float e = erff(pre / (float)M_SQRT2);
          float hg = 0.5f * pre * (1.0f + e);
          zp = zp + hg * s_w2v[k];
        }
      }
      zp += __shfl_xor(zp, 1);
      zp += __shfl_xor(zp, 2);
      zp += __shfl_xor(zp, 4);
      zp += __shfl_xor(zp, 8);
      if (l == 0) s_zc[g] = zp + s_b2v;
    }
  }
  __syncthreads();

  const int nact0 = s_nact;
  const bool cached = (nact0 <= 256);
  const int v32 = tid >> 5, g32 = tid & 31;

  auto labelOf = [&](int pos, int vv) -> int {
    return cached ? s_lab[pos * 33 + vv] : tb[(size_t)vv * N + s_gidx[pos]];
  };

  // ---------------- phase B: batched one-shot gather + initial hist ----------------
  {
    const int* row = tb + (size_t)v32 * N;
    if (cached) {
      int labs[8];
      #pragma unroll
      for (int u = 0; u < 8; ++u) {           // all loads issued before any LDS op
        int j = g32 + (u << 5);
        if (j < nact0) labs[u] = row[s_gidx[j]];
      }
      #pragma unroll
      for (int u = 0; u < 8; ++u) {
        int j = g32 + (u << 5);
        if (j < nact0) {
          s_lab[j * 33 + v32] = labs[u];
          atomicAdd(&s_h[0][v32 * HP + labs[u]], 1);
        }
      }
    } else {
      for (int j = g32; j < nact0; j += 32)
        atomicAdd(&s_h[0][v32 * HP + row[s_gidx[j]]], 1);
    }
    for (int j = tid; j < nact0; j += 1024) s_pos[j] = (unsigned short)j;
  }
  __syncthreads();

  // ---------------- heavy loop (nact > 2): all-LDS, 4 barriers/step ----------------
  int t = 0; bool stopped = false, tail = false; int hc = 0;
  while (t < T) {
    const int nact = s_nact;
    if (nact <= 2) { tail = true; break; }

    // PH1: features+MLP read s_h[hc]; idle threads zero s_h[hc^1]
    if (tid < 528) {
      const int view = tid >> 4, l = tid & 15;
      const float total = (float)nact;
      float f0, f1, f2;
      if (view == 32) {
        f0 = 1000.0f;                    // open (total>1)
        f1 = clip1000(total - 1.0f);
        f2 = clip1000(total);
      } else {
        long long sumsq = 0;
        #pragma unroll
        for (int o = l * 4; o < l * 4 + 4; ++o) {
          long long c = (long long)s_h[hc][view * HP + o];
          sumsq += c * c;
        }
        sumsq += __shfl_xor(sumsq, 1);
        sumsq += __shfl_xor(sumsq, 2);
        sumsq += __shfl_xor(sumsq, 4);
        sumsq += __shfl_xor(sumsq, 8);
        float es = (float)sumsq / total;
        float steps = (view == 0) ? 1000.0f : log2f(fmaxf(es, 1.0f));
        f0 = clip1000(steps); f1 = clip1000(es - 1.0f); f2 = clip1000(es);
      }
      float zp = 0.0f;
      {
        #pragma clang fp contract(off)
        for (int k = l * 8; k < l * 8 + 8; ++k) {
          float pre = f0 * s_w1a[k] + f1 * s_w1b[k] + f2 * s_w1c[k] + s_b1v[k];
          float e = erff(pre / (float)M_SQRT2);
          float hg = 0.5f * pre * (1.0f + e);   // exact GELU
          zp = zp + hg * s_w2v[k];
        }
      }
      zp += __shfl_xor(zp, 1);
      zp += __shfl_xor(zp, 2);
      zp += __shfl_xor(zp, 4);
      zp += __shfl_xor(zp, 8);
      if (l == 0) s_z[view] = zp + s_b2v;
    } else if (tid >= 544) {
      for (int i = tid - 544; i < 32 * HP; i += 480) s_h[hc ^ 1][i] = 0;
    }
    __syncthreads();

    // PH2: literal argmax chain
    if (tid == 0) {
      int jstar = 0; float best = s_z[0];
      for (int i = 1; i < 33; ++i) { float zz = s_z[i]; if (zz > best) { best = zz; jstar = i; } }
      int a = 0; float bv = -3.0e9f;
      for (int i = 0; i < 33; ++i) {
        float val = (i == jstar) ? 1.0f : 0.0f;
        if (i == 0) val = NEGV;
        else if (i < 32 && s_used[i]) val = NEGV;
        if (val > bv) { bv = val; a = i; }
      }
      int r = 0;
      if (a != 32) { s_used[a] = 1; r = s_resp[a]; }
      s_a = a; s_r = r; s_cnt = 0;
      out[b * T + t] = (float)a;
      out[(size_t)B * T + b * T + t] = (float)r;
    }
    __syncthreads();

    const int a = s_a, r = s_r;
    if (a == 32) { stopped = true; break; }

    // PH3/PH4: fused filter + next-hist, chunks of 256, in-place compaction
    for (int c0 = 0; c0 < nact; c0 += 256) {
      int labs[8], poss[8];
      #pragma unroll
      for (int u = 0; u < 8; ++u) {
        int j = c0 + g32 + (u << 5);
        if (j < nact) { poss[u] = s_pos[j]; labs[u] = labelOf(poss[u], v32); }
      }
      if (v32 == a) {
        #pragma unroll
        for (int u = 0; u < 8; ++u) {
          int j = c0 + g32 + (u << 5);
          if (j < nact) s_surv[j - c0] = (labs[u] == r);
        }
      }
      __syncthreads();
      if (v32 == a) {
        #pragma unroll
        for (int u = 0; u < 8; ++u) {
          int j = c0 + g32 + (u << 5);
          if (j < nact && labs[u] == r) {
            int p = atomicAdd(&s_cnt, 1);
            s_pos[p] = (unsigned short)poss[u];   // safe: p < c0+256 <= next chunk start
          }
        }
      }
      #pragma unroll
      for (int u = 0; u < 8; ++u) {
        int j = c0 + g32 + (u << 5);
        if (j < nact && s_surv[j - c0]) atomicAdd(&s_h[hc ^ 1][v32 * HP + labs[u]], 1);
      }
      __syncthreads();
    }
    if (tid == 0) s_nact = s_cnt;
    hc ^= 1;
    ++t;
    __syncthreads();
  }

  if (stopped && tid == 0) {
    for (int tt = t + 1; tt < T; ++tt) {
      out[b * T + tt] = (float)V;
      out[(size_t)B * T + b * T + tt] = 0.0f;
    }
  }

  // ---------------- single-wave serial tail (nact <= 2), constants only ----------------
  if (tail) {
    if (tid < 64) {
      const int lane = tid;
      int nact = s_nact;
      int p0 = (nact >= 1) ? (int)s_pos[0] : 0;
      int p1 = (nact == 2) ? (int)s_pos[1] : 0;
      unsigned usedmask;
      { bool ub = (lane < 32) && (s_used[lane] != 0);
        usedmask = (unsigned)__ballot(ub); }
      const float zA = s_zc[0], zB = s_zc[1], zC = s_zc[2],
                  zD = s_zc[3], zE = s_zc[4], zF = s_zc[5];
      unsigned esmask = 0;
      if (nact == 2) {
        int l0 = (lane < 32) ? labelOf(p0, lane) : 0;
        int l1 = (lane < 32) ? labelOf(p1, lane) : 0;
        esmask = (unsigned)__ballot(lane < 32 && (l0 == l1));
      }

      for (; t < T; ++t) {
        // argmax over z (first-max), then one-hot/NEG chain — uniform on all lanes
        int jstar; float best;
        if (nact == 2) {
          best = (esmask & 1u) ? zD : zC; jstar = 0;
          for (int i = 1; i < 32; ++i) {
            float zz = ((esmask >> i) & 1u) ? zA : zB;
            if (zz > best) { best = zz; jstar = i; }
          }
          if (zD > best) { best = zD; jstar = 32; }          // stop(open,total=2)
        } else if (nact == 1) {
          best = zC; jstar = 0;
          if (zB > best) { best = zB; jstar = 1; }           // views & stop all == zB
        } else {
          best = zF; jstar = 0;
          if (zE > best) { best = zE; jstar = 1; }
          if (zB > best) { best = zB; jstar = 32; }          // stop(closed,total=1)
        }
        int a = 0; float bv = -3.0e9f;
        for (int i = 0; i < 33; ++i) {
          float val = (i == jstar) ? 1.0f : 0.0f;
          if (i == 0) val = NEGV;
          else if (i < 32 && ((usedmask >> i) & 1u)) val = NEGV;
          if (val > bv) { bv = val; a = i; }
        }
        if (a == 32) {
          if (lane == 0) {
            for (int tt = t; tt < T; ++tt) {
              out[b * T + tt] = (float)V;
              out[(size_t)B * T + b * T + tt] = 0.0f;
            }
          }
          break;
        }
        usedmask |= (1u << a);
        int r = s_resp[a];
        if (lane == 0) {
          out[b * T + t] = (float)a;
          out[(size_t)B * T + b * T + t] = (float)r;
        }
        // filter (labels from LDS cache; uniform loads)
        if (nact == 2) {
          bool k0 = (labelOf(p0, a) == r);
          bool k1 = (labelOf(p1, a) == r);
          if (k0 && k1) { /* pair intact: esmask stays valid */ }
          else if (k0) { nact = 1; }
          else if (k1) { nact = 1; p0 = p1; }
          else { nact = 0; }
        } else if (nact == 1) {
          if (labelOf(p0, a) != r) nact = 0;
        }
      }
      if (lane == 0) {
        s_nact = nact;
        if (nact >= 1) s_pos[0] = (unsigned short)p0;
      }
    }
    __syncthreads();
  }

  // ---------------- epilogue: y_logits over survivors (lazy sigma) ----------------
  const int nfin = s_nact;
  for (int j = tid; j < nfin; j += 1024) {
    atomicAdd(&s_ycnt[sg[s_gidx[s_pos[j]]]], 1);
  }
  __syncthreads();
  if (tid < 32) {
    float denom = (float)(nfin > 1 ? nfin : 1);
    float q = 1.0f / denom;
    int c = s_ycnt[tid];
    float p = 0.0f;
    for (int k = 0; k < c; ++k) p = p + q;  // fl-adds of equal values == scatter-add
    out[(size_t)2 * B * T + b * 32 + tid] = logf(fmaxf(p, 1e-9f));
  }
}

extern "C" void kernel_launch(void* const* d_in, const int* in_sizes, int n_in,
                              void* d_out, int out_size, void* d_ws, size_t ws_size,
                              hipStream_t stream) {
  const int* tables   = (const int*)d_in[0];
  const int* sigma    = (const int*)d_in[1];
  const int* x        = (const int*)d_in[2];
  const int* base_obs = (const int*)d_in[3];
  const float* W1 = (const float*)d_in[4];
  const float* b1 = (const float*)d_in[5];
  const float* W2 = (const float*)d_in[6];
  const float* b2 = (const float*)d_in[7];
  const int* msteps = (const int*)d_in[8];
  float* out = (float*)d_out;

  const int B = in_sizes[2];
  const int N = in_sizes[1] / B;
  const int V = in_sizes[0] / (B * N);

  sim_kernel<<<dim3(B), dim3(1024), 0, stream>>>(
      tables, sigma, x, base_obs, W1, b1, W2, b2, msteps, out, B, V, N);
}

// Round 6
// 40.703 us; speedup vs baseline: 1.2209x; 1.2209x over previous
//
#include <hip/hip_runtime.h>
#include <math.h>

#define HP 65   // padded histogram row (kills stride-64 bank conflicts)

__device__ __forceinline__ float clip1000(float v) {
  return fminf(fmaxf(v, -1000.0f), 1000.0f);
}

// Shared MLP slice: lane l of a 16-lane group computes hidden units [8l, 8l+8),
// then a 4-step shfl tree reduces across the group. SAME tree for every call
// site -> identical features give bit-identical z (tie semantics preserved).
__device__ __noinline__ float mlp16(const float* w1a, const float* w1b,
                                    const float* w1c, const float* b1v,
                                    const float* w2v,
                                    float f0, float f1, float f2, int l) {
  float zp = 0.0f;
  {
    #pragma clang fp contract(off)
    #pragma clang loop unroll(disable)
    for (int k = l * 8; k < l * 8 + 8; ++k) {
      float pre = f0 * w1a[k] + f1 * w1b[k] + f2 * w1c[k] + b1v[k];
      float e = erff(pre / (float)M_SQRT2);
      float hg = 0.5f * pre * (1.0f + e);   // exact GELU
      zp = zp + hg * w2v[k];
    }
  }
  zp += __shfl_xor(zp, 1);
  zp += __shfl_xor(zp, 2);
  zp += __shfl_xor(zp, 4);
  zp += __shfl_xor(zp, 8);
  return zp;
}

__launch_bounds__(1024, 1)
__global__ void sim_kernel(const int* __restrict__ tables,
                           const int* __restrict__ sigma,
                           const int* __restrict__ x,
                           const int* __restrict__ base_obs,
                           const float* __restrict__ W1,
                           const float* __restrict__ b1,
                           const float* __restrict__ W2,
                           const float* __restrict__ b2,
                           const int* __restrict__ max_steps_p,
                           float* __restrict__ out,
                           int B, int V, int N)
{
  const int b = blockIdx.x;
  const int tid = threadIdx.x;
  const int T = max_steps_p[0];

  __shared__ unsigned short s_pos[8192];   // candidate positions (in-place compacted)
  __shared__ int s_gidx[8192];             // initial global indices
  __shared__ int s_lab[256 * 33];          // cached labels [pos][view], stride 33
  __shared__ int s_h[2][32 * HP];          // double-buffered histograms
  __shared__ int s_surv[256];              // per-chunk survival flags
  __shared__ float s_w1a[128], s_w1b[128], s_w1c[128], s_b1v[128], s_w2v[128];
  __shared__ float s_z[33];
  __shared__ float s_zc[6];                // precomputed tail z constants
  __shared__ int s_used[32];
  __shared__ int s_ycnt[32];
  __shared__ int s_resp[32];
  __shared__ float s_b2v;
  __shared__ int s_nact, s_cnt, s_a, s_r;

  const int* tb = tables + (size_t)b * V * N;
  const int* sg = sigma + (size_t)b * N;
  const int bo = base_obs[b];
  const int xb = x[b];

  // ---------------- phase A: weights, responses, zeros ----------------
  if (tid < 128) s_w1a[tid] = W1[tid];
  else if (tid < 256) s_w1b[tid - 128] = W1[tid];
  else if (tid < 384) s_w1c[tid - 256] = W1[tid];
  else if (tid < 512) s_b1v[tid - 384] = b1[tid - 384];
  else if (tid < 640) s_w2v[tid - 512] = W2[tid - 512];
  else if (tid == 640) s_b2v = b2[0];
  else if (tid >= 704 && tid < 736) s_resp[tid - 704] = tb[(size_t)(tid - 704) * N + xb];
  #pragma clang loop unroll(disable)
  for (int i = tid; i < 2 * 32 * HP; i += 1024) ((int*)s_h)[i] = 0;
  if (tid < 32) { s_used[tid] = 0; s_ycnt[tid] = 0; }
  if (tid == 0) s_nact = 0;
  __syncthreads();

  // ---------------- phase SCAN: m0 scan (tid<928) + tail-z consts (tid>=928) ----------------
  if (tid < 928) {
    const int4* tb4 = (const int4*)tb;
    #pragma clang loop unroll(disable)
    for (int q = tid; q < (N >> 2); q += 928) {
      int4 v4 = tb4[q]; int base = q << 2;
      if (v4.x == bo) { int p = atomicAdd(&s_nact, 1); s_gidx[p] = base; }
      if (v4.y == bo) { int p = atomicAdd(&s_nact, 1); s_gidx[p] = base + 1; }
      if (v4.z == bo) { int p = atomicAdd(&s_nact, 1); s_gidx[p] = base + 2; }
      if (v4.w == bo) { int p = atomicAdd(&s_nact, 1); s_gidx[p] = base + 3; }
    }
  } else {
    // 6 groups x 16 lanes: the only feature vectors reachable when nact<=2.
    const int g = (tid - 928) >> 4, l = (tid - 928) & 15;
    const float zcf[6][3] = {
      {1.0f, 1.0f, 2.0f},       // A: view, es=2  (log2(2)=1 exact)
      {0.0f, 0.0f, 1.0f},       // B: view es=1; stop(closed, total=1)
      {1000.0f, 0.0f, 1.0f},    // C: view0, es0=1
      {1000.0f, 1.0f, 2.0f},    // D: view0 es0=2; stop(open, total=2)
      {0.0f, -1.0f, 0.0f},      // E: view, nact=0
      {1000.0f, -1.0f, 0.0f}};  // F: view0, nact=0
    if (g < 6) {
      float zp = mlp16(s_w1a, s_w1b, s_w1c, s_b1v, s_w2v,
                       zcf[g][0], zcf[g][1], zcf[g][2], l);
      if (l == 0) s_zc[g] = zp + s_b2v;
    }
  }
  __syncthreads();

  const int nact0 = s_nact;
  const bool cached = (nact0 <= 256);
  const int v32 = tid >> 5, g32 = tid & 31;

  auto labelOf = [&](int pos, int vv) -> int {
    return cached ? s_lab[pos * 33 + vv] : tb[(size_t)vv * N + s_gidx[pos]];
  };

  // ---------------- phase B: batched one-shot gather + initial hist ----------------
  {
    const int* row = tb + (size_t)v32 * N;
    if (cached) {
      int labs[8];
      #pragma unroll
      for (int u = 0; u < 8; ++u) {           // all loads issued before any LDS op
        int j = g32 + (u << 5);
        if (j < nact0) labs[u] = row[s_gidx[j]];
      }
      #pragma unroll
      for (int u = 0; u < 8; ++u) {
        int j = g32 + (u << 5);
        if (j < nact0) {
          s_lab[j * 33 + v32] = labs[u];
          atomicAdd(&s_h[0][v32 * HP + labs[u]], 1);
        }
      }
    } else {
      #pragma clang loop unroll(disable)
      for (int j = g32; j < nact0; j += 32)
        atomicAdd(&s_h[0][v32 * HP + row[s_gidx[j]]], 1);
    }
    #pragma clang loop unroll(disable)
    for (int j = tid; j < nact0; j += 1024) s_pos[j] = (unsigned short)j;
  }
  __syncthreads();

  // ---------------- heavy loop (nact > 2): all-LDS, 4 barriers/step ----------------
  int t = 0; bool stopped = false, tail = false; int hc = 0;
  while (t < T) {
    const int nact = s_nact;
    if (nact <= 2) { tail = true; break; }

    // PH1: features+MLP read s_h[hc]; idle threads zero s_h[hc^1]
    if (tid < 528) {
      const int view = tid >> 4, l = tid & 15;
      const float total = (float)nact;
      float f0, f1, f2;
      if (view == 32) {
        f0 = 1000.0f;                    // open (total>1)
        f1 = clip1000(total - 1.0f);
        f2 = clip1000(total);
      } else {
        long long sumsq = 0;
        #pragma unroll
        for (int o = l * 4; o < l * 4 + 4; ++o) {
          long long c = (long long)s_h[hc][view * HP + o];
          sumsq += c * c;
        }
        sumsq += __shfl_xor(sumsq, 1);
        sumsq += __shfl_xor(sumsq, 2);
        sumsq += __shfl_xor(sumsq, 4);
        sumsq += __shfl_xor(sumsq, 8);
        float es = (float)sumsq / total;
        float steps = (view == 0) ? 1000.0f : log2f(fmaxf(es, 1.0f));
        f0 = clip1000(steps); f1 = clip1000(es - 1.0f); f2 = clip1000(es);
      }
      float zp = mlp16(s_w1a, s_w1b, s_w1c, s_b1v, s_w2v, f0, f1, f2, l);
      if (l == 0) s_z[view] = zp + s_b2v;
    } else if (tid >= 544) {
      #pragma clang loop unroll(disable)
      for (int i = tid - 544; i < 32 * HP; i += 480) s_h[hc ^ 1][i] = 0;
    }
    __syncthreads();

    // PH2: argmax over z (first-max), then exact integer form of the
    // one-hot -> forbid-view0 -> mask-used -> argmax chain.
    if (tid == 0) {
      int jstar = 0; float best = s_z[0];
      #pragma clang loop unroll(disable)
      for (int i = 1; i < 33; ++i) { float zz = s_z[i]; if (zz > best) { best = zz; jstar = i; } }
      int a;
      if (jstar == 32 || (jstar >= 1 && !s_used[jstar])) a = jstar;
      else {
        a = 32;                                   // fallback: stop has value 0
        #pragma clang loop unroll(disable)
        for (int i = 1; i < 32; ++i)              // first view with value 0
          if (!s_used[i]) { a = i; break; }
      }
      int r = 0;
      if (a != 32) { s_used[a] = 1; r = s_resp[a]; }
      s_a = a; s_r = r; s_cnt = 0;
      out[b * T + t] = (float)a;
      out[(size_t)B * T + b * T + t] = (float)r;
    }
    __syncthreads();

    const int a = s_a, r = s_r;
    if (a == 32) { stopped = true; break; }

    // PH3/PH4: fused filter + next-hist, chunks of 256, in-place compaction
    for (int c0 = 0; c0 < nact; c0 += 256) {
      int labs[8], poss[8];
      #pragma unroll
      for (int u = 0; u < 8; ++u) {
        int j = c0 + g32 + (u << 5);
        if (j < nact) { poss[u] = s_pos[j]; labs[u] = labelOf(poss[u], v32); }
      }
      if (v32 == a) {
        #pragma unroll
        for (int u = 0; u < 8; ++u) {
          int j = c0 + g32 + (u << 5);
          if (j < nact) s_surv[j - c0] = (labs[u] == r);
        }
      }
      __syncthreads();
      if (v32 == a) {
        #pragma unroll
        for (int u = 0; u < 8; ++u) {
          int j = c0 + g32 + (u << 5);
          if (j < nact && labs[u] == r) {
            int p = atomicAdd(&s_cnt, 1);
            s_pos[p] = (unsigned short)poss[u];   // safe: p < c0+256 <= next chunk start
          }
        }
      }
      #pragma unroll
      for (int u = 0; u < 8; ++u) {
        int j = c0 + g32 + (u << 5);
        if (j < nact && s_surv[j - c0]) atomicAdd(&s_h[hc ^ 1][v32 * HP + labs[u]], 1);
      }
      __syncthreads();
    }
    if (tid == 0) s_nact = s_cnt;
    hc ^= 1;
    ++t;
    __syncthreads();
  }

  if (stopped && tid == 0) {
    #pragma clang loop unroll(disable)
    for (int tt = t + 1; tt < T; ++tt) {
      out[b * T + tt] = (float)V;
      out[(size_t)B * T + b * T + tt] = 0.0f;
    }
  }

  // ---------------- single-wave serial tail (nact <= 2), constants only ----------------
  if (tail) {
    if (tid < 64) {
      const int lane = tid;
      int nact = s_nact;
      int p0 = (nact >= 1) ? (int)s_pos[0] : 0;
      int p1 = (nact == 2) ? (int)s_pos[1] : 0;
      unsigned usedmask;
      { bool ub = (lane < 32) && (s_used[lane] != 0);
        usedmask = (unsigned)__ballot(ub); }
      const float zA = s_zc[0], zB = s_zc[1], zC = s_zc[2],
                  zD = s_zc[3], zE = s_zc[4], zF = s_zc[5];
      unsigned esmask = 0;
      if (nact == 2) {
        int l0 = (lane < 32) ? labelOf(p0, lane) : 0;
        int l1 = (lane < 32) ? labelOf(p1, lane) : 0;
        esmask = (unsigned)__ballot(lane < 32 && (l0 == l1));
      }

      #pragma clang loop unroll(disable)
      for (; t < T; ++t) {
        // first-max over the 33 z values (structured by case), uniform on all lanes
        int jstar; float best;
        if (nact == 2) {
          best = (esmask & 1u) ? zD : zC; jstar = 0;
          #pragma clang loop unroll(disable)
          for (int i = 1; i < 32; ++i) {
            float zz = ((esmask >> i) & 1u) ? zA : zB;
            if (zz > best) { best = zz; jstar = i; }
          }
          if (zD > best) { best = zD; jstar = 32; }          // stop(open,total=2)
        } else if (nact == 1) {
          best = zC; jstar = 0;
          if (zB > best) { best = zB; jstar = 1; }           // views & stop all == zB
        } else {
          best = zF; jstar = 0;
          if (zE > best) { best = zE; jstar = 1; }
          if (zB > best) { best = zB; jstar = 32; }          // stop(closed,total=1)
        }
        // exact integer form of the one-hot/NEG/argmax chain
        int a;
        if (jstar == 32 || (jstar >= 1 && !((usedmask >> jstar) & 1u))) a = jstar;
        else {
          unsigned freeb = ~usedmask & 0x7ffffffeu;          // views 1..31 unused
          a = freeb ? (int)__builtin_ctz(freeb) : 32;
        }
        if (a == 32) {
          if (lane == 0) {
            #pragma clang loop unroll(disable)
            for (int tt = t; tt < T; ++tt) {
              out[b * T + tt] = (float)V;
              out[(size_t)B * T + b * T + tt] = 0.0f;
            }
          }
          break;
        }
        usedmask |= (1u << a);
        int r = s_resp[a];
        if (lane == 0) {
          out[b * T + t] = (float)a;
          out[(size_t)B * T + b * T + t] = (float)r;
        }
        // filter (labels from LDS cache; uniform loads)
        if (nact == 2) {
          bool k0 = (labelOf(p0, a) == r);
          bool k1 = (labelOf(p1, a) == r);
          if (k0 && k1) { /* pair intact: esmask stays valid */ }
          else if (k0) { nact = 1; }
          else if (k1) { nact = 1; p0 = p1; }
          else { nact = 0; }
        } else if (nact == 1) {
          if (labelOf(p0, a) != r) nact = 0;
        }
      }
      if (lane == 0) {
        s_nact = nact;
        if (nact >= 1) s_pos[0] = (unsigned short)p0;
      }
    }
    __syncthreads();
  }

  // ---------------- epilogue: y_logits over survivors (lazy sigma) ----------------
  const int nfin = s_nact;
  #pragma clang loop unroll(disable)
  for (int j = tid; j < nfin; j += 1024) {
    atomicAdd(&s_ycnt[sg[s_gidx[s_pos[j]]]], 1);
  }
  __syncthreads();
  if (tid < 32) {
    float denom = (float)(nfin > 1 ? nfin : 1);
    float q = 1.0f / denom;
    int c = s_ycnt[tid];
    float p = 0.0f;
    #pragma clang loop unroll(disable)
    for (int k = 0; k < c; ++k) p = p + q;  // fl-adds of equal values == scatter-add
    out[(size_t)2 * B * T + b * 32 + tid] = logf(fmaxf(p, 1e-9f));
  }
}

extern "C" void kernel_launch(void* const* d_in, const int* in_sizes, int n_in,
                              void* d_out, int out_size, void* d_ws, size_t ws_size,
                              hipStream_t stream) {
  const int* tables   = (const int*)d_in[0];
  const int* sigma    = (const int*)d_in[1];
  const int* x        = (const int*)d_in[2];
  const int* base_obs = (const int*)d_in[3];
  const float* W1 = (const float*)d_in[4];
  const float* b1 = (const float*)d_in[5];
  const float* W2 = (const float*)d_in[6];
  const float* b2 = (const float*)d_in[7];
  const int* msteps = (const int*)d_in[8];
  float* out = (float*)d_out;

  const int B = in_sizes[2];
  const int N = in_sizes[1] / B;
  const int V = in_sizes[0] / (B * N);

  sim_kernel<<<dim3(B), dim3(1024), 0, stream>>>(
      tables, sigma, x, base_obs, W1, b1, W2, b2, msteps, out, B, V, N);
}